// Round 3
// baseline (790.722 us; speedup 1.0000x reference)
//
#include <hip/hip_runtime.h>

#define NN 50000
#define NE 800000
#define HH 128
#define BN_EPS 1e-5f

typedef unsigned short u16;
typedef unsigned int u32;

static __device__ __forceinline__ float bf2f(u16 u){
  union { u32 i; float f; } v; v.i = ((u32)u) << 16; return v.f;
}
static __device__ __forceinline__ u16 f2bf(float f){
  union { float f; u32 i; } v; v.f = f;
  u32 x = v.i;
  return (u16)((x + 0x7fffu + ((x >> 16) & 1u)) >> 16);
}
static __device__ __forceinline__ void load4bf(const u16* p, float* o){
  uint2 u = *(const uint2*)p;
  o[0] = bf2f((u16)(u.x & 0xffffu));
  o[1] = bf2f((u16)(u.x >> 16));
  o[2] = bf2f((u16)(u.y & 0xffffu));
  o[3] = bf2f((u16)(u.y >> 16));
}
static __device__ __forceinline__ float sigm(float x){
  return 1.f / (1.f + __expf(-x));
}
static __device__ __forceinline__ float tanh_fast(float x){
  return 1.f - 2.f / (1.f + __expf(2.f * x));
}

// ---------------- edge preprocessing ----------------

__global__ void zero_kernel(int* __restrict__ p, int n){
  int i = blockIdx.x * blockDim.x + threadIdx.x;
  if (i < n) p[i] = 0;
}

__global__ void hist_kernel(const int* __restrict__ dst, int* __restrict__ counts, int E){
  int e = blockIdx.x * blockDim.x + threadIdx.x;
  if (e < E) atomicAdd(&counts[dst[e]], 1);
}

__global__ __launch_bounds__(1024) void scan_kernel(
    const int* __restrict__ counts, int* __restrict__ offs,
    int* __restrict__ cursor, int n){
  __shared__ int part[1024];
  int tid = threadIdx.x;
  int chunk = (n + 1023) >> 10;             // 49
  int begin = tid * chunk;
  int end   = begin + chunk; if (end > n) end = n;
  int s = 0;
  for (int i = begin; i < end && i >= 0; i++) s += counts[i];
  part[tid] = s;
  __syncthreads();
  for (int off = 1; off < 1024; off <<= 1){
    int v = (tid >= off) ? part[tid - off] : 0;
    __syncthreads();
    part[tid] += v;
    __syncthreads();
  }
  int excl = part[tid] - s;
  for (int i = begin; i < end && i >= 0; i++){
    offs[i] = excl; cursor[i] = excl;
    excl += counts[i];
  }
}

__global__ void scatter_kernel(const int* __restrict__ src, const int* __restrict__ dst,
                               const float* __restrict__ w, int* __restrict__ cursor,
                               int* __restrict__ es, float* __restrict__ ews, int E){
  int e = blockIdx.x * blockDim.x + threadIdx.x;
  if (e < E){
    int d = dst[e];
    int pos = atomicAdd(&cursor[d], 1);
    es[pos]  = src[e];
    ews[pos] = w[e];
  }
}

// ---------------- support = x @ gcn_weight  (N x 128), fp32 in -> bf16 out --------
// BM=64, BN=128, BK=32, 256 threads, thread tile 8x4.
__global__ __launch_bounds__(256) void support_gemm(
    const float* __restrict__ x, const float* __restrict__ W,
    u16* __restrict__ support, int N){
  __shared__ float As[32 * 68];    // [kk][m], stride 68 (16B-aligned rows)
  __shared__ float Bs[32 * 128];   // [kk][h]
  int tid = threadIdx.x;
  int row0 = blockIdx.x * 64;
  int tr = tid >> 5, tc = tid & 31;
  int r0 = tr * 8, c0 = tc * 4;
  float acc[8][4];
#pragma unroll
  for (int i = 0; i < 8; i++)
#pragma unroll
    for (int j = 0; j < 4; j++) acc[i][j] = 0.f;

  for (int k0 = 0; k0 < 128; k0 += 32){
    // stage B: W[k0..k0+31][0..127], already [k][h] layout
#pragma unroll
    for (int rep = 0; rep < 4; rep++){
      int f = rep * 256 + tid;
      int kk = f >> 5, hq = f & 31;
      float4 v = *(const float4*)(W + (size_t)(k0 + kk) * 128 + hq * 4);
      *(float4*)&Bs[kk * 128 + hq * 4] = v;
    }
    // stage A (transposed): x rows row0..row0+63, k chunk
#pragma unroll
    for (int rep = 0; rep < 2; rep++){
      int f = rep * 256 + tid;
      int m = f >> 3, kq = f & 7;
      int row = row0 + m;
      float4 v = make_float4(0.f, 0.f, 0.f, 0.f);
      if (row < N) v = *(const float4*)(x + (size_t)row * 128 + k0 + kq * 4);
      As[(kq * 4 + 0) * 68 + m] = v.x;
      As[(kq * 4 + 1) * 68 + m] = v.y;
      As[(kq * 4 + 2) * 68 + m] = v.z;
      As[(kq * 4 + 3) * 68 + m] = v.w;
    }
    __syncthreads();
#pragma unroll
    for (int kk = 0; kk < 32; kk++){
      float4 b  = *(const float4*)&Bs[kk * 128 + c0];
      float4 a0 = *(const float4*)&As[kk * 68 + r0];
      float4 a1 = *(const float4*)&As[kk * 68 + r0 + 4];
      float av[8] = {a0.x, a0.y, a0.z, a0.w, a1.x, a1.y, a1.z, a1.w};
      float bv[4] = {b.x, b.y, b.z, b.w};
#pragma unroll
      for (int i = 0; i < 8; i++)
#pragma unroll
        for (int j = 0; j < 4; j++) acc[i][j] = fmaf(av[i], bv[j], acc[i][j]);
    }
    __syncthreads();
  }
#pragma unroll
  for (int i = 0; i < 8; i++){
    int row = row0 + r0 + i;
    if (row < N){
      uint2 u;
      u.x = (u32)f2bf(acc[i][0]) | ((u32)f2bf(acc[i][1]) << 16);
      u.y = (u32)f2bf(acc[i][2]) | ((u32)f2bf(acc[i][3]) << 16);
      *(uint2*)(support + (size_t)row * 128 + c0) = u;
    }
  }
}

// ---------------- CSR aggregate + relu + bias + BN -> h_bn (bf16) ----------------
// one wave per node; lane covers 2 columns
__global__ __launch_bounds__(256) void agg_bn(
    const u16* __restrict__ support, const int* __restrict__ es,
    const float* __restrict__ ews, const int* __restrict__ offs,
    const int* __restrict__ counts,
    const float* __restrict__ bias, const float* __restrict__ gamma,
    const float* __restrict__ beta, const float* __restrict__ mean,
    const float* __restrict__ var,
    u16* __restrict__ hbn, int N){
  int wid = blockIdx.x * 4 + (threadIdx.x >> 6);
  int lane = threadIdx.x & 63;
  if (wid >= N) return;
  int start = offs[wid];
  int deg   = counts[wid];
  int c = lane * 2;
  float a0 = 0.f, a1 = 0.f;
  for (int e = 0; e < deg; e++){
    int s   = es[start + e];
    float g = ews[start + e];
    u32 u = *(const u32*)(support + (size_t)s * HH + c);
    a0 = fmaf(g, bf2f((u16)(u & 0xffffu)), a0);
    a1 = fmaf(g, bf2f((u16)(u >> 16)), a1);
  }
  float h0 = fmaxf(a0, 0.f) + bias[c];
  float h1 = fmaxf(a1, 0.f) + bias[c + 1];
  float s0 = gamma[c]     * rsqrtf(var[c]     + BN_EPS);
  float s1 = gamma[c + 1] * rsqrtf(var[c + 1] + BN_EPS);
  float r0 = (h0 - mean[c])     * s0 + beta[c];
  float r1 = (h1 - mean[c + 1]) * s1 + beta[c + 1];
  u32 pack = (u32)f2bf(r0) | ((u32)f2bf(r1) << 16);
  *(u32*)(hbn + (size_t)wid * HH + c) = pack;
}

// ---------------- gates = hbn @ x2h_w^T + hx @ h2h_w^T (+biases) -> LSTM ----------------
// BM=16 rows, BN=512 (full, enables fused LSTM), BK=16, K=256 virtual concat.
// A source: hbn (bf16, k<128) then hx (fp32, k>=128). B: fp32 weights.
// Output: fp32 (hy then cy, concatenated flat).
__global__ __launch_bounds__(256) void gates_lstm(
    const u16* __restrict__ hbn, const float* __restrict__ hx,
    const float* __restrict__ x2h_w, const float* __restrict__ h2h_w,
    const float* __restrict__ x2h_b, const float* __restrict__ h2h_b,
    const float* __restrict__ cx, float* __restrict__ out, int N){
  __shared__ float As[16 * 20];    // [kk][m], stride 20 (16B-aligned rows)
  __shared__ float Bs[16 * 512];   // [kk][j]; reused as gates tile [16][512] in epilogue
  int tid = threadIdx.x;
  int row0 = blockIdx.x * 16;
  int tr = tid >> 6, tc = tid & 63;
  int r0 = tr * 4;
  int c0 = tc * 4, c1 = c0 + 256;
  float accA[4][4], accB[4][4];
#pragma unroll
  for (int i = 0; i < 4; i++)
#pragma unroll
    for (int j = 0; j < 4; j++){ accA[i][j] = 0.f; accB[i][j] = 0.f; }

  for (int k0 = 0; k0 < 256; k0 += 16){
    const float* Bsrc = (k0 < 128) ? x2h_w : h2h_w;
    int kb0 = k0 & 127;
    // stage B: 512 rows(j) x 16 k, via 4x4 register transpose -> b128 LDS writes
#pragma unroll
    for (int rep = 0; rep < 2; rep++){
      int t = rep * 256 + tid;
      int jb = t & 127, kb = t >> 7;   // kb in 0..3
      float4 wv[4];
#pragma unroll
      for (int i = 0; i < 4; i++)
        wv[i] = *(const float4*)(Bsrc + (size_t)(jb * 4 + i) * 128 + kb0 + kb * 4);
      *(float4*)&Bs[(kb * 4 + 0) * 512 + jb * 4] = make_float4(wv[0].x, wv[1].x, wv[2].x, wv[3].x);
      *(float4*)&Bs[(kb * 4 + 1) * 512 + jb * 4] = make_float4(wv[0].y, wv[1].y, wv[2].y, wv[3].y);
      *(float4*)&Bs[(kb * 4 + 2) * 512 + jb * 4] = make_float4(wv[0].z, wv[1].z, wv[2].z, wv[3].z);
      *(float4*)&Bs[(kb * 4 + 3) * 512 + jb * 4] = make_float4(wv[0].w, wv[1].w, wv[2].w, wv[3].w);
    }
    // stage A: 16 rows x 16 k (threads 0..63)
    if (tid < 64){
      int m = tid >> 2, kq = tid & 3;
      int row = row0 + m;
      float v[4] = {0.f, 0.f, 0.f, 0.f};
      if (row < N){
        if (k0 < 128){
          load4bf(hbn + (size_t)row * 128 + kb0 + kq * 4, v);
        } else {
          float4 t = *(const float4*)(hx + (size_t)row * 128 + kb0 + kq * 4);
          v[0] = t.x; v[1] = t.y; v[2] = t.z; v[3] = t.w;
        }
      }
#pragma unroll
      for (int j = 0; j < 4; j++) As[(kq * 4 + j) * 20 + m] = v[j];
    }
    __syncthreads();
#pragma unroll
    for (int kk = 0; kk < 16; kk++){
      float4 a  = *(const float4*)&As[kk * 20 + r0];
      float4 b0 = *(const float4*)&Bs[kk * 512 + c0];
      float4 b1 = *(const float4*)&Bs[kk * 512 + c1];
      float av[4]  = {a.x, a.y, a.z, a.w};
      float bv0[4] = {b0.x, b0.y, b0.z, b0.w};
      float bv1[4] = {b1.x, b1.y, b1.z, b1.w};
#pragma unroll
      for (int i = 0; i < 4; i++)
#pragma unroll
        for (int j = 0; j < 4; j++){
          accA[i][j] = fmaf(av[i], bv0[j], accA[i][j]);
          accB[i][j] = fmaf(av[i], bv1[j], accB[i][j]);
        }
    }
    __syncthreads();
  }

  // write gates tile into Bs (as gtile[16][512])
#pragma unroll
  for (int i = 0; i < 4; i++){
    float* row = &Bs[(r0 + i) * 512];
    *(float4*)&row[c0] = make_float4(accA[i][0], accA[i][1], accA[i][2], accA[i][3]);
    *(float4*)&row[c1] = make_float4(accB[i][0], accB[i][1], accB[i][2], accB[i][3]);
  }
  __syncthreads();

  const size_t NHtot = (size_t)N * HH;
#pragma unroll
  for (int it = 0; it < 8; it++){
    int q = it * 256 + tid;
    int nl = q >> 7, h = q & 127;
    int n = row0 + nl;
    if (n < N){
      float gi = Bs[nl * 512 + h]       + x2h_b[h]       + h2h_b[h];
      float gf = Bs[nl * 512 + 128 + h] + x2h_b[128 + h] + h2h_b[128 + h];
      float gg = Bs[nl * 512 + 256 + h] + x2h_b[256 + h] + h2h_b[256 + h];
      float go = Bs[nl * 512 + 384 + h] + x2h_b[384 + h] + h2h_b[384 + h];
      float is = sigm(gi);
      float fs = sigm(gf);
      float gt = tanh_fast(gg);
      float os = sigm(go);
      float co = cx[(size_t)n * HH + h];
      float cyv = co * fs + is * gt;
      float hyv = os * tanh_fast(cyv);
      out[(size_t)n * HH + h]         = hyv;
      out[NHtot + (size_t)n * HH + h] = cyv;
    }
  }
}

// ---------------- launch ----------------

extern "C" void kernel_launch(void* const* d_in, const int* in_sizes, int n_in,
                              void* d_out, int out_size, void* d_ws, size_t ws_size,
                              hipStream_t stream){
  const float* x     = (const float*)d_in[0];
  const float* hx    = (const float*)d_in[1];
  const float* cx    = (const float*)d_in[2];
  const int*   esrc  = (const int*)d_in[3];
  const int*   edst  = (const int*)d_in[4];
  const float* ew    = (const float*)d_in[5];
  const float* gcn_w = (const float*)d_in[6];
  const float* bias  = (const float*)d_in[7];
  const float* x2hw  = (const float*)d_in[8];
  const float* x2hb  = (const float*)d_in[9];
  const float* h2hw  = (const float*)d_in[10];
  const float* h2hb  = (const float*)d_in[11];
  const float* bn_g  = (const float*)d_in[12];
  const float* bn_b  = (const float*)d_in[13];
  const float* bn_m  = (const float*)d_in[14];
  const float* bn_v  = (const float*)d_in[15];
  float* out = (float*)d_out;

  char* w = (char*)d_ws;
  u16* support = (u16*)w; w += (((size_t)NN * HH * 2) + 255) & ~(size_t)255;
  u16* hbn     = (u16*)w; w += (((size_t)NN * HH * 2) + 255) & ~(size_t)255;
  int* counts  = (int*)w; w += (((size_t)NN * 4) + 255) & ~(size_t)255;
  int* offs    = (int*)w; w += (((size_t)NN * 4) + 255) & ~(size_t)255;
  int* cursor  = (int*)w; w += (((size_t)NN * 4) + 255) & ~(size_t)255;
  int* es      = (int*)w; w += (((size_t)NE * 4) + 255) & ~(size_t)255;
  float* ews   = (float*)w; w += (((size_t)NE * 4) + 255) & ~(size_t)255;

  zero_kernel<<<(NN + 255) / 256, 256, 0, stream>>>(counts, NN);
  hist_kernel<<<(NE + 255) / 256, 256, 0, stream>>>(edst, counts, NE);
  scan_kernel<<<1, 1024, 0, stream>>>(counts, offs, cursor, NN);
  scatter_kernel<<<(NE + 255) / 256, 256, 0, stream>>>(esrc, edst, ew, cursor, es, ews, NE);
  support_gemm<<<(NN + 63) / 64, 256, 0, stream>>>(x, gcn_w, support, NN);
  agg_bn<<<(NN + 3) / 4, 256, 0, stream>>>(support, es, ews, offs, counts,
                                           bias, bn_g, bn_b, bn_m, bn_v, hbn, NN);
  gates_lstm<<<(NN + 15) / 16, 256, 0, stream>>>(hbn, hx, x2hw, h2hw, x2hb, h2hb,
                                                 cx, out, NN);
}

// Round 4
// 550.162 us; speedup vs baseline: 1.4373x; 1.4373x over previous
//
#include <hip/hip_runtime.h>

#define NN 50000
#define NE 800000
#define HH 128
#define BN_EPS 1e-5f
#define BPAD 40   // padded k-stride (u16) for MFMA LDS tiles: bank stride 20 -> 2-way (free)

typedef unsigned short u16;
typedef unsigned int u32;
typedef short bf16x8 __attribute__((ext_vector_type(8)));
typedef float f32x4 __attribute__((ext_vector_type(4)));

static __device__ __forceinline__ float bf2f(u16 u){
  union { u32 i; float f; } v; v.i = ((u32)u) << 16; return v.f;
}
static __device__ __forceinline__ u16 f2bf(float f){
  union { float f; u32 i; } v; v.f = f;
  u32 x = v.i;
  return (u16)((x + 0x7fffu + ((x >> 16) & 1u)) >> 16);
}
static __device__ __forceinline__ float sigm(float x){
  return 1.f / (1.f + __expf(-x));
}
static __device__ __forceinline__ float tanh_fast(float x){
  return 1.f - 2.f / (1.f + __expf(2.f * x));
}

// ---------------- edge preprocessing ----------------

__global__ void zero_kernel(int* __restrict__ p, int n){
  int i = blockIdx.x * blockDim.x + threadIdx.x;
  if (i < n) p[i] = 0;
}

__global__ void hist_kernel(const int* __restrict__ dst, int* __restrict__ counts, int E){
  int e = blockIdx.x * blockDim.x + threadIdx.x;
  if (e < E) atomicAdd(&counts[dst[e]], 1);
}

__global__ __launch_bounds__(1024) void scan_kernel(
    const int* __restrict__ counts, int* __restrict__ offs,
    int* __restrict__ cursor, int n){
  __shared__ int part[1024];
  int tid = threadIdx.x;
  int chunk = (n + 1023) >> 10;
  int begin = tid * chunk;
  int end   = begin + chunk; if (end > n) end = n;
  int s = 0;
  for (int i = begin; i < end && i >= 0; i++) s += counts[i];
  part[tid] = s;
  __syncthreads();
  for (int off = 1; off < 1024; off <<= 1){
    int v = (tid >= off) ? part[tid - off] : 0;
    __syncthreads();
    part[tid] += v;
    __syncthreads();
  }
  int excl = part[tid] - s;
  for (int i = begin; i < end && i >= 0; i++){
    offs[i] = excl; cursor[i] = excl;
    excl += counts[i];
  }
}

__global__ void scatter_kernel(const int* __restrict__ src, const int* __restrict__ dst,
                               const float* __restrict__ w, int* __restrict__ cursor,
                               int* __restrict__ es, float* __restrict__ ews, int E){
  int e = blockIdx.x * blockDim.x + threadIdx.x;
  if (e < E){
    int d = dst[e];
    int pos = atomicAdd(&cursor[d], 1);
    es[pos]  = src[e];
    ews[pos] = w[e];
  }
}

// ---------------- pack gate weights to bf16 [n][k] (B^T layout) + bias sums ------

__global__ void prep_w(const float* __restrict__ x2hw, const float* __restrict__ h2hw,
                       const float* __restrict__ x2hb, const float* __restrict__ h2hb,
                       u16* __restrict__ wcat, float* __restrict__ bsum){
  int i = blockIdx.x * blockDim.x + threadIdx.x;   // 0..131071
  int n = i >> 8, k = i & 255;
  float v = (k < 128) ? x2hw[n * 128 + k] : h2hw[n * 128 + (k - 128)];
  wcat[i] = f2bf(v);
  if (i < 512) bsum[i] = x2hb[i] + h2hb[i];
}

// ---------------- support = x @ gcn_weight  (N x 128), fp32 in -> bf16 out --------

__global__ __launch_bounds__(256) void support_gemm(
    const float* __restrict__ x, const float* __restrict__ W,
    u16* __restrict__ support, int N){
  __shared__ float As[32 * 68];
  __shared__ float Bs[32 * 128];
  int tid = threadIdx.x;
  int row0 = blockIdx.x * 64;
  int tr = tid >> 5, tc = tid & 31;
  int r0 = tr * 8, c0 = tc * 4;
  float acc[8][4];
#pragma unroll
  for (int i = 0; i < 8; i++)
#pragma unroll
    for (int j = 0; j < 4; j++) acc[i][j] = 0.f;

  for (int k0 = 0; k0 < 128; k0 += 32){
#pragma unroll
    for (int rep = 0; rep < 4; rep++){
      int f = rep * 256 + tid;
      int kk = f >> 5, hq = f & 31;
      float4 v = *(const float4*)(W + (size_t)(k0 + kk) * 128 + hq * 4);
      *(float4*)&Bs[kk * 128 + hq * 4] = v;
    }
#pragma unroll
    for (int rep = 0; rep < 2; rep++){
      int f = rep * 256 + tid;
      int m = f >> 3, kq = f & 7;
      int row = row0 + m;
      float4 v = make_float4(0.f, 0.f, 0.f, 0.f);
      if (row < N) v = *(const float4*)(x + (size_t)row * 128 + k0 + kq * 4);
      As[(kq * 4 + 0) * 68 + m] = v.x;
      As[(kq * 4 + 1) * 68 + m] = v.y;
      As[(kq * 4 + 2) * 68 + m] = v.z;
      As[(kq * 4 + 3) * 68 + m] = v.w;
    }
    __syncthreads();
#pragma unroll
    for (int kk = 0; kk < 32; kk++){
      float4 b  = *(const float4*)&Bs[kk * 128 + c0];
      float4 a0 = *(const float4*)&As[kk * 68 + r0];
      float4 a1 = *(const float4*)&As[kk * 68 + r0 + 4];
      float av[8] = {a0.x, a0.y, a0.z, a0.w, a1.x, a1.y, a1.z, a1.w};
      float bv[4] = {b.x, b.y, b.z, b.w};
#pragma unroll
      for (int i = 0; i < 8; i++)
#pragma unroll
        for (int j = 0; j < 4; j++) acc[i][j] = fmaf(av[i], bv[j], acc[i][j]);
    }
    __syncthreads();
  }
#pragma unroll
  for (int i = 0; i < 8; i++){
    int row = row0 + r0 + i;
    if (row < N){
      uint2 u;
      u.x = (u32)f2bf(acc[i][0]) | ((u32)f2bf(acc[i][1]) << 16);
      u.y = (u32)f2bf(acc[i][2]) | ((u32)f2bf(acc[i][3]) << 16);
      *(uint2*)(support + (size_t)row * 128 + c0) = u;
    }
  }
}

// ---------------- CSR aggregate + relu + bias + BN -> h_bn (bf16) ----------------

__global__ __launch_bounds__(256) void agg_bn(
    const u16* __restrict__ support, const int* __restrict__ es,
    const float* __restrict__ ews, const int* __restrict__ offs,
    const int* __restrict__ counts,
    const float* __restrict__ bias, const float* __restrict__ gamma,
    const float* __restrict__ beta, const float* __restrict__ mean,
    const float* __restrict__ var,
    u16* __restrict__ hbn, int N){
  int wid = blockIdx.x * 4 + (threadIdx.x >> 6);
  int lane = threadIdx.x & 63;
  if (wid >= N) return;
  int start = offs[wid];
  int deg   = counts[wid];
  int c = lane * 2;
  float a0 = 0.f, a1 = 0.f;
  for (int e = 0; e < deg; e++){
    int s   = es[start + e];
    float g = ews[start + e];
    u32 u = *(const u32*)(support + (size_t)s * HH + c);
    a0 = fmaf(g, bf2f((u16)(u & 0xffffu)), a0);
    a1 = fmaf(g, bf2f((u16)(u >> 16)), a1);
  }
  float h0 = fmaxf(a0, 0.f) + bias[c];
  float h1 = fmaxf(a1, 0.f) + bias[c + 1];
  float s0 = gamma[c]     * rsqrtf(var[c]     + BN_EPS);
  float s1 = gamma[c + 1] * rsqrtf(var[c + 1] + BN_EPS);
  float r0 = (h0 - mean[c])     * s0 + beta[c];
  float r1 = (h1 - mean[c + 1]) * s1 + beta[c + 1];
  u32 pack = (u32)f2bf(r0) | ((u32)f2bf(r1) << 16);
  *(u32*)(hbn + (size_t)wid * HH + c) = pack;
}

// ---------------- gates GEMM on MFMA + fused LSTM epilogue ----------------
// block = 64 rows x 512 cols, 4 waves; wave = 16 rows x all 32 n-tiles.
// A = [hbn | bf16(hx)] (N x 256), B^T = wcat[512][256] bf16.
// Epilogue is register-local: gates i/f/g/o live at tiles tb, tb+8, tb+16, tb+24
// in the same lane/reg for a given (row, h).
__global__ __launch_bounds__(256) void gates_mfma(
    const u16* __restrict__ hbn, const float* __restrict__ hx,
    const u16* __restrict__ wcat, const float* __restrict__ bsum,
    const float* __restrict__ cx, float* __restrict__ out, int N){
  __shared__ u16 As[64 * BPAD];
  __shared__ u16 Bs[512 * BPAD];
  __shared__ float bs[512];
  int tid = threadIdx.x;
  int wave = tid >> 6, lane = tid & 63;
  int row0 = blockIdx.x * 64;
  {
    float2 b2 = *(const float2*)(bsum + tid * 2);
    bs[tid * 2]     = b2.x;
    bs[tid * 2 + 1] = b2.y;
  }
  f32x4 acc[32];
#pragma unroll
  for (int t = 0; t < 32; t++) acc[t] = (f32x4){0.f, 0.f, 0.f, 0.f};

  for (int k0 = 0; k0 < 256; k0 += 32){
    // stage B: 512 rows(n) x 32 k, 64 B/row; wcat already [n][k] bf16
#pragma unroll
    for (int rep = 0; rep < 2; rep++){
      int n = rep * 256 + tid;
      const u16* src = wcat + (size_t)n * 256 + k0;
      uint4 v0 = *(const uint4*)(src);
      uint4 v1 = *(const uint4*)(src + 8);
      uint4 v2 = *(const uint4*)(src + 16);
      uint4 v3 = *(const uint4*)(src + 24);
      u16* d = Bs + n * BPAD;
      *(uint4*)(d)      = v0;
      *(uint4*)(d + 8)  = v1;
      *(uint4*)(d + 16) = v2;
      *(uint4*)(d + 24) = v3;
    }
    // stage A: 64 rows x 32 k (hbn bf16 direct; hx fp32 -> bf16)
    {
      int m = tid >> 2, c = tid & 3;
      int row = row0 + m;
      u16 tmp[8];
      if (row < N){
        if (k0 < 128){
          *(uint4*)tmp = *(const uint4*)(hbn + (size_t)row * 128 + k0 + c * 8);
        } else {
          const float* s = hx + (size_t)row * 128 + (k0 - 128) + c * 8;
          float4 f0 = *(const float4*)(s);
          float4 f1 = *(const float4*)(s + 4);
          tmp[0] = f2bf(f0.x); tmp[1] = f2bf(f0.y); tmp[2] = f2bf(f0.z); tmp[3] = f2bf(f0.w);
          tmp[4] = f2bf(f1.x); tmp[5] = f2bf(f1.y); tmp[6] = f2bf(f1.z); tmp[7] = f2bf(f1.w);
        }
      } else {
#pragma unroll
        for (int j = 0; j < 8; j++) tmp[j] = 0;
      }
      *(uint4*)(As + m * BPAD + c * 8) = *(uint4*)tmp;
    }
    __syncthreads();
    int mloc = wave * 16 + (lane & 15);
    int quad = lane >> 4;
    bf16x8 afrag = *(bf16x8*)(As + mloc * BPAD + quad * 8);
#pragma unroll
    for (int t = 0; t < 32; t++){
      int n = t * 16 + (lane & 15);
      bf16x8 bfrag = *(bf16x8*)(Bs + n * BPAD + quad * 8);
      acc[t] = __builtin_amdgcn_mfma_f32_16x16x32_bf16(afrag, bfrag, acc[t], 0, 0, 0);
    }
    __syncthreads();
  }

  // fused LSTM epilogue (register-local gates)
  int quad = lane >> 4, lc = lane & 15;
  const size_t NH = (size_t)N * HH;
#pragma unroll
  for (int j = 0; j < 4; j++){
    int r = row0 + wave * 16 + quad * 4 + j;
    if (r < N){
#pragma unroll
      for (int tb = 0; tb < 8; tb++){
        int h = tb * 16 + lc;
        float gi = acc[tb][j]      + bs[h];
        float gf = acc[tb + 8][j]  + bs[128 + h];
        float gg = acc[tb + 16][j] + bs[256 + h];
        float go = acc[tb + 24][j] + bs[384 + h];
        float is = sigm(gi), fs = sigm(gf), gt = tanh_fast(gg), os = sigm(go);
        float co = cx[(size_t)r * HH + h];
        float cyv = co * fs + is * gt;
        out[(size_t)r * HH + h]      = os * tanh_fast(cyv);
        out[NH + (size_t)r * HH + h] = cyv;
      }
    }
  }
}

// ---------------- launch ----------------

extern "C" void kernel_launch(void* const* d_in, const int* in_sizes, int n_in,
                              void* d_out, int out_size, void* d_ws, size_t ws_size,
                              hipStream_t stream){
  const float* x     = (const float*)d_in[0];
  const float* hx    = (const float*)d_in[1];
  const float* cx    = (const float*)d_in[2];
  const int*   esrc  = (const int*)d_in[3];
  const int*   edst  = (const int*)d_in[4];
  const float* ew    = (const float*)d_in[5];
  const float* gcn_w = (const float*)d_in[6];
  const float* bias  = (const float*)d_in[7];
  const float* x2hw  = (const float*)d_in[8];
  const float* x2hb  = (const float*)d_in[9];
  const float* h2hw  = (const float*)d_in[10];
  const float* h2hb  = (const float*)d_in[11];
  const float* bn_g  = (const float*)d_in[12];
  const float* bn_b  = (const float*)d_in[13];
  const float* bn_m  = (const float*)d_in[14];
  const float* bn_v  = (const float*)d_in[15];
  float* out = (float*)d_out;

  char* w = (char*)d_ws;
  u16* support = (u16*)w; w += (((size_t)NN * HH * 2) + 255) & ~(size_t)255;
  u16* hbn     = (u16*)w; w += (((size_t)NN * HH * 2) + 255) & ~(size_t)255;
  int* counts  = (int*)w; w += (((size_t)NN * 4) + 255) & ~(size_t)255;
  int* offs    = (int*)w; w += (((size_t)NN * 4) + 255) & ~(size_t)255;
  int* cursor  = (int*)w; w += (((size_t)NN * 4) + 255) & ~(size_t)255;
  int* es      = (int*)w; w += (((size_t)NE * 4) + 255) & ~(size_t)255;
  float* ews   = (float*)w; w += (((size_t)NE * 4) + 255) & ~(size_t)255;
  u16* wcat    = (u16*)w; w += (((size_t)512 * 256 * 2) + 255) & ~(size_t)255;
  float* bsum  = (float*)w; w += (((size_t)512 * 4) + 255) & ~(size_t)255;

  prep_w<<<512, 256, 0, stream>>>(x2hw, h2hw, x2hb, h2hb, wcat, bsum);
  zero_kernel<<<(NN + 255) / 256, 256, 0, stream>>>(counts, NN);
  hist_kernel<<<(NE + 255) / 256, 256, 0, stream>>>(edst, counts, NE);
  scan_kernel<<<1, 1024, 0, stream>>>(counts, offs, cursor, NN);
  scatter_kernel<<<(NE + 255) / 256, 256, 0, stream>>>(esrc, edst, ew, cursor, es, ews, NE);
  support_gemm<<<(NN + 63) / 64, 256, 0, stream>>>(x, gcn_w, support, NN);
  agg_bn<<<(NN + 3) / 4, 256, 0, stream>>>(support, es, ews, offs, counts,
                                           bias, bn_g, bn_b, bn_m, bn_v, hbn, NN);
  gates_mfma<<<(NN + 63) / 64, 256, 0, stream>>>(hbn, hx, wcat, bsum, cx, out, NN);
}